// Round 19
// baseline (194.924 us; speedup 1.0000x reference)
//
#include <hip/hip_runtime.h>
#include <hip/hip_fp16.h>

#define H 4
#define C 128
#define FOUT 512

typedef __attribute__((ext_vector_type(8))) short s16x8;
typedef __attribute__((ext_vector_type(4))) float f32x4;
typedef __attribute__((ext_vector_type(4))) int i32x4;
typedef __attribute__((ext_vector_type(2))) int i32x2;

// CK-style raw buffer-load intrinsics (32-bit voffset addressing)
__device__ int amd_buf_load_i32(i32x4 rsrc, int voffset, int soffset, int aux) __asm("llvm.amdgcn.raw.buffer.load.i32");
__device__ i32x2 amd_buf_load_i32x2(i32x4 rsrc, int voffset, int soffset, int aux) __asm("llvm.amdgcn.raw.buffer.load.v2i32");
__device__ i32x4 amd_buf_load_i32x4(i32x4 rsrc, int voffset, int soffset, int aux) __asm("llvm.amdgcn.raw.buffer.load.v4i32");

__device__ __forceinline__ i32x4 make_rsrc(const void* p, unsigned int bytes) {
    i32x4 r;
    r.x = (int)(unsigned int)(unsigned long long)p;
    r.y = (int)(unsigned int)(((unsigned long long)p) >> 32);
    r.z = (int)bytes;          // num_records; OOB load returns 0
    r.w = 0x00020000;          // raw untyped dword access
    return r;
}

__device__ __forceinline__ unsigned int f2bf_bits(float f) {
    unsigned int u = __float_as_uint(f);
    u += 0x7fffu + ((u >> 16) & 1u);
    return u >> 16;
}
__device__ __forceinline__ unsigned int pack2bf(unsigned int u0, unsigned int u1) {
    unsigned int r0 = (u0 + 0x7fffu + ((u0 >> 16) & 1u)) >> 16;
    unsigned int r1 = (u1 + 0x7fffu + ((u1 >> 16) & 1u)) & 0xffff0000u;
    return r0 | r1;
}
__device__ __forceinline__ unsigned int pack2bf_f(float a, float b) {
    return f2bf_bits(a) | (f2bf_bits(b) << 16);
}
__device__ __forceinline__ float bflo(unsigned int u) { return __uint_as_float(u << 16); }
__device__ __forceinline__ float bfhi(unsigned int u) { return __uint_as_float(u & 0xffff0000u); }
__device__ __forceinline__ float leaky(float x) { return (x >= 0.f) ? x : 0.2f * x; }
__device__ __forceinline__ __half2 u2h2(unsigned int u) {
    union { unsigned int u; __half2 h; } c; c.u = u; return c.h;
}
__device__ __forceinline__ unsigned int h22u(__half2 h) {
    union { __half2 h; unsigned int u; } c; c.h = h; return c.u;
}
__device__ __forceinline__ unsigned int pkrtz_bits(float a, float b) {
    auto v = __builtin_amdgcn_cvt_pkrtz(a, b);
    union { decltype(v) h; unsigned int u; } c; c.h = v; return c.u;
}

// ---------------- prep: convert weights (blocks 0-255) || zero counts (blocks 256+) ----------------
__global__ void prep_zero(const float* __restrict__ W1, const float* __restrict__ W2,
                          unsigned short* __restrict__ Wt1, unsigned short* __restrict__ Wt2,
                          int* __restrict__ counts, int N) {
    int b = blockIdx.x;
    if (b < 256) {
        int i = b * 256 + threadIdx.x;
        if (i < 128 * 512) {
            int c = i >> 7, k = i & 127;
            Wt1[i] = (unsigned short)f2bf_bits(W1[(size_t)k * FOUT + c]);
            Wt2[i] = (unsigned short)f2bf_bits(W2[(size_t)k * FOUT + c]);
        }
    } else {
        int i = (b - 256) * 256 + threadIdx.x;
        if (i < N) counts[i] = 0;
    }
}

// ---------------- hist (standalone) ----------------
__global__ void hist_kernel(const int* __restrict__ ei, int E, int N, int* __restrict__ counts) {
    int e = blockIdx.x * blockDim.x + threadIdx.x;
    int M = E + N;
    if (e >= M) return;
    int d = (e < E) ? ei[E + e] : (e - E);
    atomicAdd(&counts[d], 1);
}

// ---------------- scan body (256 threads, dense counts, int4) ----------------
__device__ __forceinline__ void scan_body(const int* __restrict__ counts,
                                          int* __restrict__ row_off,
                                          int* __restrict__ cursor, int N, int* part) {
    int t = threadIdx.x;
    int chunk = (((N + 255) >> 8) + 3) & ~3;
    int b = t * chunk; if (b > N) b = N;
    int e = b + chunk; if (e > N) e = N;
    int s = 0;
    int i = b;
    for (; i + 3 < e; i += 4) {
        int4 v = *(const int4*)&counts[i];
        s += v.x + v.y + v.z + v.w;
    }
    for (; i < e; ++i) s += counts[i];
    part[t] = s;
    __syncthreads();
    for (int off = 1; off < 256; off <<= 1) {
        int v = (t >= off) ? part[t - off] : 0;
        __syncthreads();
        part[t] += v;
        __syncthreads();
    }
    int run = (t == 0) ? 0 : part[t - 1];
    i = b;
    for (; i + 3 < e; i += 4) {
        int4 c = *(const int4*)&counts[i];
        int4 r;
        r.x = run; r.y = run + c.x; r.z = r.y + c.y; r.w = r.z + c.z;
        *(int4*)&row_off[i] = r;
        *(int4*)&cursor[i] = r;
        run = r.w + c.w;
    }
    for (; i < e; ++i) { row_off[i] = run; cursor[i] = run; run += counts[i]; }
    if (t == 255) row_off[N] = part[255];
}

// ---------------- scatter (standalone) ----------------
__global__ void scatter_kernel(const int* __restrict__ ei, int E, int N,
                               int* __restrict__ cursor, int* __restrict__ csr_src) {
    int e = blockIdx.x * blockDim.x + threadIdx.x;
    int M = E + N;
    if (e >= M) return;
    int s = (e < E) ? ei[e] : (e - E);
    int d = (e < E) ? ei[E + e] : (e - E);
    int pos = atomicAdd(&cursor[d], 1);
    csr_src[pos] = s;
}

// ---------------- MFMA GEMM body: 64-row blocks, LDS-staged A, swapped operands ----------------
// IS_X: A = x (fp32 rows, stride 520B, +8B). Else: A = hout f16 slabs, fused head-mean+bias (combine1).
template <bool IS_X>
__device__ __forceinline__ void gemm_body(int h, int r0, const void* __restrict__ Asrc,
                                          const float* __restrict__ bias, int Nrows,
                                          const unsigned short* __restrict__ Bt,
                                          const float* __restrict__ a_src,
                                          const float* __restrict__ a_dst,
                                          unsigned short* __restrict__ Xh,
                                          float* __restrict__ alpha_s,
                                          float* __restrict__ alpha_d,
                                          int Npad, i32x4* __restrict__ AsTile,
                                          float (*albuf)[2][16][2][2]) {
    int t = threadIdx.x;
    int lane = t & 63;
    int wv = t >> 6;
    int wr = wv >> 1, wc = wv & 1;
    int lr = lane & 15;
    int ksel = lane >> 4;

    // ---- stage A tile (64 rows x 128 ch, coalesced) ----
    #pragma unroll
    for (int i = 0; i < 4; ++i) {
        int q = t + i * 256;          // 1024 x 16B chunks
        int row = q >> 4, cb = q & 15;
        int gr = r0 + row;
        i32x4 v;
        if constexpr (IS_X) {
            i32x4 rA = make_rsrc(Asrc, (unsigned int)Nrows * 520u);
            int base = gr * 520 + 8 + cb * 32;
            i32x2 u0 = amd_buf_load_i32x2(rA, base, 0, 0);
            i32x2 u1 = amd_buf_load_i32x2(rA, base + 8, 0, 0);
            i32x2 u2 = amd_buf_load_i32x2(rA, base + 16, 0, 0);
            i32x2 u3 = amd_buf_load_i32x2(rA, base + 24, 0, 0);
            v.x = (int)pack2bf((unsigned int)u0.x, (unsigned int)u0.y);
            v.y = (int)pack2bf((unsigned int)u1.x, (unsigned int)u1.y);
            v.z = (int)pack2bf((unsigned int)u2.x, (unsigned int)u2.y);
            v.w = (int)pack2bf((unsigned int)u3.x, (unsigned int)u3.y);
        } else {
            // fused combine: A[row][c] = 0.25 * sum_h hout_f16[h*2+chalf][row][c64] + bias[c]
            if (gr < Nrows) {
                int chalf = cb >> 3;
                int c8 = (cb & 7) * 8;             // channel offset within the 64-ch half
                const uint4* hb = (const uint4*)Asrc;
                uint4 a0 = hb[((size_t)(0 + chalf) * Npad + gr) * 8 + (cb & 7)];
                uint4 a1 = hb[((size_t)(2 + chalf) * Npad + gr) * 8 + (cb & 7)];
                uint4 a2 = hb[((size_t)(4 + chalf) * Npad + gr) * 8 + (cb & 7)];
                uint4 a3 = hb[((size_t)(6 + chalf) * Npad + gr) * 8 + (cb & 7)];
                __half2 s0 = __hadd2(__hadd2(u2h2(a0.x), u2h2(a1.x)), __hadd2(u2h2(a2.x), u2h2(a3.x)));
                __half2 s1 = __hadd2(__hadd2(u2h2(a0.y), u2h2(a1.y)), __hadd2(u2h2(a2.y), u2h2(a3.y)));
                __half2 s2 = __hadd2(__hadd2(u2h2(a0.z), u2h2(a1.z)), __hadd2(u2h2(a2.z), u2h2(a3.z)));
                __half2 s3 = __hadd2(__hadd2(u2h2(a0.w), u2h2(a1.w)), __hadd2(u2h2(a2.w), u2h2(a3.w)));
                const float* bp = bias + chalf * 64 + c8;
                float4 b0 = *(const float4*)bp;
                float4 b1 = *(const float4*)(bp + 4);
                float2 f0 = __half22float2(s0), f1 = __half22float2(s1);
                float2 f2 = __half22float2(s2), f3 = __half22float2(s3);
                v.x = (int)pack2bf_f(0.25f * f0.x + b0.x, 0.25f * f0.y + b0.y);
                v.y = (int)pack2bf_f(0.25f * f1.x + b0.z, 0.25f * f1.y + b0.w);
                v.z = (int)pack2bf_f(0.25f * f2.x + b1.x, 0.25f * f2.y + b1.y);
                v.w = (int)pack2bf_f(0.25f * f3.x + b1.z, 0.25f * f3.y + b1.w);
            } else {
                v = (i32x4){0, 0, 0, 0};
            }
        }
        AsTile[row * 16 + (cb ^ (row & 7))] = v;
    }
    __syncthreads();

    f32x4 acc[2][4];
    #pragma unroll
    for (int i = 0; i < 2; ++i)
        #pragma unroll
        for (int j = 0; j < 4; ++j) acc[i][j] = (f32x4){0.f, 0.f, 0.f, 0.f};

    const s16x8* Bb = (const s16x8*)(Bt + (size_t)(h * 128 + wc * 64 + lr) * C);

    #pragma unroll
    for (int ks = 0; ks < 4; ++ks) {
        int cb = ks * 4 + ksel;
        s16x8 af[2], bf[4];
        #pragma unroll
        for (int i = 0; i < 2; ++i) {
            int rowl = wr * 32 + i * 16 + lr;
            af[i] = __builtin_bit_cast(s16x8, AsTile[rowl * 16 + (cb ^ (rowl & 7))]);
        }
        #pragma unroll
        for (int j = 0; j < 4; ++j) bf[j] = Bb[(size_t)(j * 16) * 16 + cb];
        #pragma unroll
        for (int i = 0; i < 2; ++i)
            #pragma unroll
            for (int j = 0; j < 4; ++j)
                acc[i][j] = __builtin_amdgcn_mfma_f32_16x16x32_bf16(bf[j], af[i], acc[i][j], 0, 0, 0);
    }

    float4 avj[4], dvj[4];
    #pragma unroll
    for (int j = 0; j < 4; ++j) {
        int cc = h * C + wc * 64 + j * 16 + ksel * 4;
        avj[j] = *(const float4*)&a_src[cc];
        dvj[j] = *(const float4*)&a_dst[cc];
    }

    unsigned short* slabp = Xh + (size_t)(h * 2 + wc) * Npad * 64;
    float ps[2] = {0.f, 0.f}, pd[2] = {0.f, 0.f};
    #pragma unroll
    for (int i = 0; i < 2; ++i) {
        int gr = r0 + wr * 32 + i * 16 + lr;
        #pragma unroll
        for (int j = 0; j < 4; ++j) {
            f32x4 a4 = acc[i][j];
            ps[i] += a4[0] * avj[j].x + a4[1] * avj[j].y + a4[2] * avj[j].z + a4[3] * avj[j].w;
            pd[i] += a4[0] * dvj[j].x + a4[1] * dvj[j].y + a4[2] * dvj[j].z + a4[3] * dvj[j].w;
            uint2 o;
            o.x = pkrtz_bits(a4[0], a4[1]);
            o.y = pkrtz_bits(a4[2], a4[3]);
            *(uint2*)(slabp + (size_t)gr * 64 + j * 16 + ksel * 4) = o;
        }
        ps[i] += __shfl_xor(ps[i], 16); ps[i] += __shfl_xor(ps[i], 32);
        pd[i] += __shfl_xor(pd[i], 16); pd[i] += __shfl_xor(pd[i], 32);
    }
    if (lane < 16) {
        #pragma unroll
        for (int i = 0; i < 2; ++i) {
            albuf[wr][i][lane][wc][0] = ps[i];
            albuf[wr][i][lane][wc][1] = pd[i];
        }
    }
    __syncthreads();

    if (t < 128) {
        int rid = t >> 1, which = t & 1;
        int wr2 = rid >> 5, rem = rid & 31, i2 = rem >> 4, l2 = rem & 15;
        float v = albuf[wr2][i2][l2][0][which] + albuf[wr2][i2][l2][1][which];
        int gr = r0 + wr2 * 32 + i2 * 16 + l2;
        if (gr < Nrows) {
            if (which) alpha_d[gr * H + h] = v;
            else       alpha_s[gr * H + h] = v;
        }
    }
}

// ---------------- gemm1 || scan (block 0 = scan, hidden under the GEMM grid) ----------------
__global__ __launch_bounds__(256) void gemm1_scan(const float* __restrict__ x, int N,
                                                  const unsigned short* __restrict__ Wt1,
                                                  const float* __restrict__ as1,
                                                  const float* __restrict__ ad1,
                                                  unsigned short* __restrict__ Xh,
                                                  float* __restrict__ alpha_s,
                                                  float* __restrict__ alpha_d, int Npad,
                                                  const int* __restrict__ counts,
                                                  int* __restrict__ row_off,
                                                  int* __restrict__ cursor) {
    __shared__ i32x4 AsTile[1024];
    __shared__ float albuf[2][2][16][2][2];
    int b = blockIdx.x;
    if (b == 0) {
        scan_body(counts, row_off, cursor, N, (int*)AsTile);
        return;
    }
    int gb = b - 1;
    gemm_body<true>(gb & 3, (gb >> 2) * 64, x, nullptr, N, Wt1, as1, ad1, Xh, alpha_s, alpha_d,
                    Npad, AsTile, albuf);
}

// ---------------- gemm2: fused combine1 (hout f16 -> head-mean + b1 -> A) ----------------
__global__ __launch_bounds__(256) void gemm2_kernel(const unsigned short* __restrict__ hout, int N,
                                                    const float* __restrict__ b1,
                                                    const unsigned short* __restrict__ Wt2,
                                                    const float* __restrict__ as2,
                                                    const float* __restrict__ ad2,
                                                    unsigned short* __restrict__ Xh,
                                                    float* __restrict__ alpha_s,
                                                    float* __restrict__ alpha_d, int Npad) {
    __shared__ i32x4 AsTile[1024];
    __shared__ float albuf[2][2][16][2][2];
    int gb = blockIdx.x;
    gemm_body<false>(gb & 3, (gb >> 2) * 64, hout, b1, N, Wt2, as2, ad2, Xh, alpha_s, alpha_d,
                     Npad, AsTile, albuf);
}

// ---------------- fused per-node max + per-edge packed weights: 4 nodes/wave, 16 lanes/node ----------------
// pk[h][e] = (f16(w) << 16) | src   (src < 65536)
__global__ __launch_bounds__(256) void attn_kernel(const float4* __restrict__ as4,
                                                   const float4* __restrict__ ad4,
                                                   const int* __restrict__ row_off,
                                                   const int* __restrict__ csr_src,
                                                   unsigned int* __restrict__ pk, int N, int M) {
    int n = blockIdx.x * 16 + (threadIdx.x >> 4);
    if (n >= N) return;
    int l = threadIdx.x & 15;
    int beg = row_off[n], end = row_off[n + 1];
    float4 mx = make_float4(-1e30f, -1e30f, -1e30f, -1e30f);
    for (int e = beg + l; e < end; e += 16) {
        float4 a = as4[csr_src[e]];
        mx.x = fmaxf(mx.x, a.x); mx.y = fmaxf(mx.y, a.y);
        mx.z = fmaxf(mx.z, a.z); mx.w = fmaxf(mx.w, a.w);
    }
    #pragma unroll
    for (int off = 8; off >= 1; off >>= 1) {
        mx.x = fmaxf(mx.x, __shfl_xor(mx.x, off));
        mx.y = fmaxf(mx.y, __shfl_xor(mx.y, off));
        mx.z = fmaxf(mx.z, __shfl_xor(mx.z, off));
        mx.w = fmaxf(mx.w, __shfl_xor(mx.w, off));
    }
    float4 d = ad4[n];
    float4 m;
    m.x = leaky(mx.x + d.x); m.y = leaky(mx.y + d.y);
    m.z = leaky(mx.z + d.z); m.w = leaky(mx.w + d.w);
    for (int e = beg + l; e < end; e += 16) {
        int s = csr_src[e];
        float4 a = as4[s];   // L1-hot from pass 0
        unsigned int su = (unsigned int)s;
        unsigned int w0 = (unsigned int)__half_as_ushort(__float2half(__expf(leaky(a.x + d.x) - m.x)));
        unsigned int w1 = (unsigned int)__half_as_ushort(__float2half(__expf(leaky(a.y + d.y) - m.y)));
        unsigned int w2 = (unsigned int)__half_as_ushort(__float2half(__expf(leaky(a.z + d.z) - m.z)));
        unsigned int w3 = (unsigned int)__half_as_ushort(__float2half(__expf(leaky(a.w + d.w) - m.w)));
        pk[e]                 = (w0 << 16) | su;
        pk[(size_t)M + e]     = (w1 << 16) | su;
        pk[(size_t)2 * M + e] = (w2 << 16) | su;
        pk[(size_t)3 * M + e] = (w3 << 16) | su;
    }
}

// ---------------- aggregation v13: full-head waves (2 slabs), dwordx4 gathers ----------------
__global__ __launch_bounds__(256) void aggregate_v13(const unsigned short* __restrict__ xh,
                                                     const unsigned int* __restrict__ pk,
                                                     const int* __restrict__ row_off,
                                                     unsigned short* __restrict__ hout,
                                                     int N, int Npad, int M) {
    int i = blockIdx.x;
    int h = i & 3;
    int t = threadIdx.x;
    int wv = t >> 6;
    int lane = t & 63;
    int slot = lane >> 4;
    int l16 = lane & 15;
    int nbase = ((i >> 2) * 4 + wv) * 2;
    if (nbase >= N) return;

    i32x4 rx = make_rsrc(xh + (size_t)(h * 2) * Npad * 64, (unsigned int)Npad * 256u);
    i32x4 rp = make_rsrc(pk + (size_t)h * M, (unsigned int)M * 4u);
    int lcoff = (l16 >> 3) * (Npad * 128) + (l16 & 7) * 16;
    int slot4 = slot << 2;
    int nend = (nbase + 2 < N) ? nbase + 2 : N;

    for (int n = nbase; n < nend; ++n) {
        int beg = row_off[n], end = row_off[n + 1];
        __half2 a0 = u2h2(0), a1 = u2h2(0), a2 = u2h2(0), a3 = u2h2(0), den2 = u2h2(0);

        for (int ebase = beg; ebase < end; ebase += 64) {
            int p = amd_buf_load_i32(rp, (ebase + lane) << 2, 0, 0);
            int nrem = end - ebase;
            int jmax = ((nrem < 64 ? nrem : 64) + 7) >> 3;
            for (int j = 0; j < jmax; ++j) {
                int addr = (j << 5) + slot4;
                int sp0 = __builtin_amdgcn_ds_bpermute(addr, p);
                int sp1 = __builtin_amdgcn_ds_bpermute(addr + 16, p);
                int e0 = ebase + (j << 3) + slot;
                i32x4 ga = amd_buf_load_i32x4(rx, ((sp0 & 0xffff) << 7) + lcoff, 0, 0);
                i32x4 gb = amd_buf_load_i32x4(rx, ((sp1 & 0xffff) << 7) + lcoff, 0, 0);
                unsigned int wa2 = __builtin_amdgcn_perm(sp0, sp0, 0x03020302);
                unsigned int wb2 = __builtin_amdgcn_perm(sp1, sp1, 0x03020302);
                if (e0 >= end) wa2 = 0u;
                if (e0 + 4 >= end) wb2 = 0u;
                __half2 wha = u2h2(wa2), whb = u2h2(wb2);
                a0 = __hfma2(wha, u2h2((unsigned int)ga.x), a0);
                a1 = __hfma2(wha, u2h2((unsigned int)ga.y), a1);
                a2 = __hfma2(wha, u2h2((unsigned int)ga.z), a2);
                a3 = __hfma2(wha, u2h2((unsigned int)ga.w), a3);
                a0 = __hfma2(whb, u2h2((unsigned int)gb.x), a0);
                a1 = __hfma2(whb, u2h2((unsigned int)gb.y), a1);
                a2 = __hfma2(whb, u2h2((unsigned int)gb.z), a2);
                a3 = __hfma2(whb, u2h2((unsigned int)gb.w), a3);
                den2 = __hadd2(den2, wha);
                den2 = __hadd2(den2, whb);
            }
        }

        // cross-slot reduce (lane bits 4,5): 5 packed values x 2 levels
        #pragma unroll
        for (int off = 16; off <= 32; off <<= 1) {
            a0 = __hadd2(a0, u2h2((unsigned int)__shfl_xor((int)h22u(a0), off)));
            a1 = __hadd2(a1, u2h2((unsigned int)__shfl_xor((int)h22u(a1), off)));
            a2 = __hadd2(a2, u2h2((unsigned int)__shfl_xor((int)h22u(a2), off)));
            a3 = __hadd2(a3, u2h2((unsigned int)__shfl_xor((int)h22u(a3), off)));
            den2 = __hadd2(den2, u2h2((unsigned int)__shfl_xor((int)h22u(den2), off)));
        }

        if (slot == 0) {
            float2 f0 = __half22float2(a0), f1 = __half22float2(a1);
            float2 f2 = __half22float2(a2), f3 = __half22float2(a3);
            float inv = 1.f / __half2float(__low2half(den2));
            uint4 o;
            o.x = pkrtz_bits(f0.x * inv, f0.y * inv);   // f16 out
            o.y = pkrtz_bits(f1.x * inv, f1.y * inv);
            o.z = pkrtz_bits(f2.x * inv, f2.y * inv);
            o.w = pkrtz_bits(f3.x * inv, f3.y * inv);
            ((uint4*)hout)[((size_t)(h * 2 + (l16 >> 3)) * Npad + n) * 8 + (l16 & 7)] = o;
        }
    }
}

// ---------------- head mean + bias -> bf16 feats (hout read as f16) + out init for pair ----------------
__global__ void combine_kernel(const unsigned short* __restrict__ hout,
                               const float* __restrict__ bias,
                               unsigned short* __restrict__ featsbf, int N, int Npad,
                               float* __restrict__ out, const float* __restrict__ fcb, int P) {
    int i = blockIdx.x * blockDim.x + threadIdx.x;   // dword index over [N][64]
    if (i < P) out[i] = fcb[0];
    if (i >= N * 64) return;
    int n = i >> 6, c2 = i & 63;
    int chalf = c2 >> 5, ld = c2 & 31;
    const unsigned int* hp = (const unsigned int*)hout;
    float lo = 0.f, hi = 0.f;
    #pragma unroll
    for (int h = 0; h < 4; ++h) {
        unsigned int v = hp[((size_t)(h * 2 + chalf) * Npad + n) * 32 + ld];
        float2 f = __half22float2(u2h2(v));
        lo += f.x; hi += f.y;
    }
    lo = 0.25f * lo + bias[c2 * 2];
    hi = 0.25f * hi + bias[c2 * 2 + 1];
    ((unsigned int*)featsbf)[(size_t)n * 64 + c2] = f2bf_bits(lo) | (f2bf_bits(hi) << 16);
}

// ---------------- pairwise scorer: chalf-split, XCD parity pinned, atomic combine ----------------
__global__ __launch_bounds__(256) void pair_kernel(const unsigned short* __restrict__ featsbf,
                                                   const float* __restrict__ x,
                                                   const int* __restrict__ idx, int P,
                                                   const float* __restrict__ fc_w,
                                                   float* __restrict__ out) {
    int chalf = blockIdx.x & 1;
    int p = (blockIdx.x >> 1) * 16 + (threadIdx.x >> 4);
    int l = threadIdx.x & 15;
    if (p >= P) return;
    int i0 = idx[p], i1 = idx[P + p];
    uint2 a = ((const uint2*)featsbf)[(size_t)i0 * 32 + chalf * 16 + l];
    uint2 b = ((const uint2*)featsbf)[(size_t)i1 * 32 + chalf * 16 + l];
    float s = bflo(a.x) * bflo(b.x) + bfhi(a.x) * bfhi(b.x)
            + bflo(a.y) * bflo(b.y) + bfhi(a.y) * bfhi(b.y);
    s += __shfl_xor(s, 1); s += __shfl_xor(s, 2);
    s += __shfl_xor(s, 4); s += __shfl_xor(s, 8);
    if (l == 0) {
        float v = fc_w[0] * s;
        if (chalf == 0) {
            float2 c0 = *(const float2*)&x[(size_t)i0 * 130];
            float2 c1 = *(const float2*)&x[(size_t)i1 * 130];
            float dx = c0.x - c1.x;
            float dy = c0.y - c1.y;
            v += fc_w[1] * (dx * dx + dy * dy);
        }
        atomicAdd(&out[p], v);
    }
}

extern "C" void kernel_launch(void* const* d_in, const int* in_sizes, int n_in,
                              void* d_out, int out_size, void* d_ws, size_t ws_size,
                              hipStream_t stream) {
    const float* x   = (const float*)d_in[0];
    const int*   ei  = (const int*)d_in[1];
    const int*   idx = (const int*)d_in[2];
    const float* W1  = (const float*)d_in[3];
    const float* as1 = (const float*)d_in[4];
    const float* ad1 = (const float*)d_in[5];
    const float* b1  = (const float*)d_in[6];
    const float* W2  = (const float*)d_in[7];
    const float* as2 = (const float*)d_in[8];
    const float* ad2 = (const float*)d_in[9];
    const float* b2  = (const float*)d_in[10];
    const float* fcw = (const float*)d_in[11];
    const float* fcb = (const float*)d_in[12];
    float* out = (float*)d_out;

    const int N = in_sizes[0] / 130;
    const int E = in_sizes[1] / 2;
    const int P = in_sizes[2] / 2;
    const int M = E + N;
    const int Npad = (N + 127) & ~127;

    char* ws = (char*)d_ws;
    size_t off = 0;
    auto alloc = [&](size_t bytes) -> void* {
        void* p = ws + off;
        off += (bytes + 255) & ~(size_t)255;
        return p;
    };
    unsigned short* xh_f16  = (unsigned short*)alloc((size_t)Npad * FOUT * 2);
    unsigned short* hout    = (unsigned short*)alloc((size_t)Npad * FOUT * 2);
    unsigned short* featsbf = (unsigned short*)alloc((size_t)Npad * C * 2);
    unsigned short* Wt1     = (unsigned short*)alloc((size_t)128 * FOUT * 2);
    unsigned short* Wt2     = (unsigned short*)alloc((size_t)128 * FOUT * 2);
    float*          alpha_s = (float*)alloc((size_t)N * H * 4);
    float*          alpha_d = (float*)alloc((size_t)N * H * 4);
    unsigned int*   pk      = (unsigned int*)alloc((size_t)M * H * 4);
    int*            row_off = (int*)alloc((size_t)(N + 1) * 4);
    int*            cursor  = (int*)alloc((size_t)N * 4);
    int*            counts  = (int*)alloc((size_t)N * 4);
    int*            csr_src = (int*)alloc((size_t)M * 4);

    const int zeroBlocks = (N + 255) / 256;
    const int histBlocks = (M + 255) / 256;
    const int gemmBlocks = 4 * (Npad / 64);
    int aggGrid = ((N + 7) / 8) * 4;
    int cmbGrid = (N * 64 + 255) / 256;

    // (weights-convert || zero counts), hist, (gemm1 || scan), scatter
    prep_zero<<<256 + zeroBlocks, 256, 0, stream>>>(W1, W2, Wt1, Wt2, counts, N);
    hist_kernel<<<histBlocks, 256, 0, stream>>>(ei, E, N, counts);
    gemm1_scan<<<1 + gemmBlocks, 256, 0, stream>>>(x, N, Wt1, as1, ad1, xh_f16,
                                                   alpha_s, alpha_d, Npad,
                                                   counts, row_off, cursor);
    scatter_kernel<<<histBlocks, 256, 0, stream>>>(ei, E, N, cursor, csr_src);

    // layer 1
    attn_kernel<<<(N + 15) / 16, 256, 0, stream>>>((const float4*)alpha_s, (const float4*)alpha_d,
                                                   row_off, csr_src, pk, N, M);
    aggregate_v13<<<aggGrid, 256, 0, stream>>>(xh_f16, pk, row_off, hout, N, Npad, M);

    // layer 2 (gemm2 reads hout f16 directly, fused combine1 with bias b1)
    gemm2_kernel<<<gemmBlocks, 256, 0, stream>>>(hout, N, b1, Wt2, as2, ad2, xh_f16,
                                                 alpha_s, alpha_d, Npad);
    attn_kernel<<<(N + 15) / 16, 256, 0, stream>>>((const float4*)alpha_s, (const float4*)alpha_d,
                                                   row_off, csr_src, pk, N, M);
    aggregate_v13<<<aggGrid, 256, 0, stream>>>(xh_f16, pk, row_off, hout, N, Npad, M);
    combine_kernel<<<cmbGrid, 256, 0, stream>>>(hout, b2, featsbf, N, Npad, out, fcb, P);

    // pairwise output (chalf-split, accumulates into out initialized by combine above)
    pair_kernel<<<((P + 15) / 16) * 2, 256, 0, stream>>>(featsbf, x, idx, P, fcw, out);
}

// Round 20
// 193.784 us; speedup vs baseline: 1.0059x; 1.0059x over previous
//
#include <hip/hip_runtime.h>
#include <hip/hip_fp16.h>

#define H 4
#define C 128
#define FOUT 512

typedef __attribute__((ext_vector_type(8))) short s16x8;
typedef __attribute__((ext_vector_type(4))) float f32x4;
typedef __attribute__((ext_vector_type(4))) int i32x4;
typedef __attribute__((ext_vector_type(2))) int i32x2;

// CK-style raw buffer-load intrinsics (32-bit voffset addressing)
__device__ int amd_buf_load_i32(i32x4 rsrc, int voffset, int soffset, int aux) __asm("llvm.amdgcn.raw.buffer.load.i32");
__device__ i32x2 amd_buf_load_i32x2(i32x4 rsrc, int voffset, int soffset, int aux) __asm("llvm.amdgcn.raw.buffer.load.v2i32");
__device__ i32x4 amd_buf_load_i32x4(i32x4 rsrc, int voffset, int soffset, int aux) __asm("llvm.amdgcn.raw.buffer.load.v4i32");

__device__ __forceinline__ i32x4 make_rsrc(const void* p, unsigned int bytes) {
    i32x4 r;
    r.x = (int)(unsigned int)(unsigned long long)p;
    r.y = (int)(unsigned int)(((unsigned long long)p) >> 32);
    r.z = (int)bytes;          // num_records; OOB load returns 0
    r.w = 0x00020000;          // raw untyped dword access
    return r;
}

__device__ __forceinline__ unsigned int f2bf_bits(float f) {
    unsigned int u = __float_as_uint(f);
    u += 0x7fffu + ((u >> 16) & 1u);
    return u >> 16;
}
__device__ __forceinline__ unsigned int pack2bf(unsigned int u0, unsigned int u1) {
    unsigned int r0 = (u0 + 0x7fffu + ((u0 >> 16) & 1u)) >> 16;
    unsigned int r1 = (u1 + 0x7fffu + ((u1 >> 16) & 1u)) & 0xffff0000u;
    return r0 | r1;
}
__device__ __forceinline__ unsigned int pack2bf_f(float a, float b) {
    return f2bf_bits(a) | (f2bf_bits(b) << 16);
}
__device__ __forceinline__ float bflo(unsigned int u) { return __uint_as_float(u << 16); }
__device__ __forceinline__ float bfhi(unsigned int u) { return __uint_as_float(u & 0xffff0000u); }
__device__ __forceinline__ float leaky(float x) { return (x >= 0.f) ? x : 0.2f * x; }
__device__ __forceinline__ __half2 u2h2(unsigned int u) {
    union { unsigned int u; __half2 h; } c; c.u = u; return c.h;
}
__device__ __forceinline__ unsigned int h22u(__half2 h) {
    union { __half2 h; unsigned int u; } c; c.h = h; return c.u;
}
__device__ __forceinline__ unsigned int pkrtz_bits(float a, float b) {
    auto v = __builtin_amdgcn_cvt_pkrtz(a, b);
    union { decltype(v) h; unsigned int u; } c; c.h = v; return c.u;
}

// ---------------- prep: convert weights (blocks 0-255) || zero counts (blocks 256+) ----------------
__global__ void prep_zero(const float* __restrict__ W1, const float* __restrict__ W2,
                          unsigned short* __restrict__ Wt1, unsigned short* __restrict__ Wt2,
                          int* __restrict__ counts, int N) {
    int b = blockIdx.x;
    if (b < 256) {
        int i = b * 256 + threadIdx.x;
        if (i < 128 * 512) {
            int c = i >> 7, k = i & 127;
            Wt1[i] = (unsigned short)f2bf_bits(W1[(size_t)k * FOUT + c]);
            Wt2[i] = (unsigned short)f2bf_bits(W2[(size_t)k * FOUT + c]);
        }
    } else {
        int i = (b - 256) * 256 + threadIdx.x;
        if (i < N) counts[i] = 0;
    }
}

// ---------------- hist (standalone) ----------------
__global__ void hist_kernel(const int* __restrict__ ei, int E, int N, int* __restrict__ counts) {
    int e = blockIdx.x * blockDim.x + threadIdx.x;
    int M = E + N;
    if (e >= M) return;
    int d = (e < E) ? ei[E + e] : (e - E);
    atomicAdd(&counts[d], 1);
}

// ---------------- scan body (256 threads, dense counts, int4) ----------------
__device__ __forceinline__ void scan_body(const int* __restrict__ counts,
                                          int* __restrict__ row_off,
                                          int* __restrict__ cursor, int N, int* part) {
    int t = threadIdx.x;
    int chunk = (((N + 255) >> 8) + 3) & ~3;
    int b = t * chunk; if (b > N) b = N;
    int e = b + chunk; if (e > N) e = N;
    int s = 0;
    int i = b;
    for (; i + 3 < e; i += 4) {
        int4 v = *(const int4*)&counts[i];
        s += v.x + v.y + v.z + v.w;
    }
    for (; i < e; ++i) s += counts[i];
    part[t] = s;
    __syncthreads();
    for (int off = 1; off < 256; off <<= 1) {
        int v = (t >= off) ? part[t - off] : 0;
        __syncthreads();
        part[t] += v;
        __syncthreads();
    }
    int run = (t == 0) ? 0 : part[t - 1];
    i = b;
    for (; i + 3 < e; i += 4) {
        int4 c = *(const int4*)&counts[i];
        int4 r;
        r.x = run; r.y = run + c.x; r.z = r.y + c.y; r.w = r.z + c.z;
        *(int4*)&row_off[i] = r;
        *(int4*)&cursor[i] = r;
        run = r.w + c.w;
    }
    for (; i < e; ++i) { row_off[i] = run; cursor[i] = run; run += counts[i]; }
    if (t == 255) row_off[N] = part[255];
}

// ---------------- scatter (standalone) ----------------
__global__ void scatter_kernel(const int* __restrict__ ei, int E, int N,
                               int* __restrict__ cursor, int* __restrict__ csr_src) {
    int e = blockIdx.x * blockDim.x + threadIdx.x;
    int M = E + N;
    if (e >= M) return;
    int s = (e < E) ? ei[e] : (e - E);
    int d = (e < E) ? ei[E + e] : (e - E);
    int pos = atomicAdd(&cursor[d], 1);
    csr_src[pos] = s;
}

// ---------------- MFMA GEMM body: 64-row blocks, LDS-staged A, swapped operands ----------------
// IS_X: A = x (fp32 rows, stride 520B, +8B). Else: A = hout f16 slabs, fused head-mean+bias (combine1).
template <bool IS_X>
__device__ __forceinline__ void gemm_body(int h, int r0, const void* __restrict__ Asrc,
                                          const float* __restrict__ bias, int Nrows,
                                          const unsigned short* __restrict__ Bt,
                                          const float* __restrict__ a_src,
                                          const float* __restrict__ a_dst,
                                          unsigned short* __restrict__ Xh,
                                          float* __restrict__ alpha_s,
                                          float* __restrict__ alpha_d,
                                          int Npad, i32x4* __restrict__ AsTile,
                                          float (*albuf)[2][16][2][2]) {
    int t = threadIdx.x;
    int lane = t & 63;
    int wv = t >> 6;
    int wr = wv >> 1, wc = wv & 1;
    int lr = lane & 15;
    int ksel = lane >> 4;

    // ---- stage A tile (64 rows x 128 ch, coalesced) ----
    #pragma unroll
    for (int i = 0; i < 4; ++i) {
        int q = t + i * 256;          // 1024 x 16B chunks
        int row = q >> 4, cb = q & 15;
        int gr = r0 + row;
        i32x4 v;
        if constexpr (IS_X) {
            i32x4 rA = make_rsrc(Asrc, (unsigned int)Nrows * 520u);
            int base = gr * 520 + 8 + cb * 32;
            i32x2 u0 = amd_buf_load_i32x2(rA, base, 0, 0);
            i32x2 u1 = amd_buf_load_i32x2(rA, base + 8, 0, 0);
            i32x2 u2 = amd_buf_load_i32x2(rA, base + 16, 0, 0);
            i32x2 u3 = amd_buf_load_i32x2(rA, base + 24, 0, 0);
            v.x = (int)pack2bf((unsigned int)u0.x, (unsigned int)u0.y);
            v.y = (int)pack2bf((unsigned int)u1.x, (unsigned int)u1.y);
            v.z = (int)pack2bf((unsigned int)u2.x, (unsigned int)u2.y);
            v.w = (int)pack2bf((unsigned int)u3.x, (unsigned int)u3.y);
        } else {
            // fused combine: A[row][c] = 0.25 * sum_h hout_f16[h*2+chalf][row][c64] + bias[c]
            if (gr < Nrows) {
                int chalf = cb >> 3;
                int c8 = (cb & 7) * 8;             // channel offset within the 64-ch half
                const uint4* hb = (const uint4*)Asrc;
                uint4 a0 = hb[((size_t)(0 + chalf) * Npad + gr) * 8 + (cb & 7)];
                uint4 a1 = hb[((size_t)(2 + chalf) * Npad + gr) * 8 + (cb & 7)];
                uint4 a2 = hb[((size_t)(4 + chalf) * Npad + gr) * 8 + (cb & 7)];
                uint4 a3 = hb[((size_t)(6 + chalf) * Npad + gr) * 8 + (cb & 7)];
                __half2 s0 = __hadd2(__hadd2(u2h2(a0.x), u2h2(a1.x)), __hadd2(u2h2(a2.x), u2h2(a3.x)));
                __half2 s1 = __hadd2(__hadd2(u2h2(a0.y), u2h2(a1.y)), __hadd2(u2h2(a2.y), u2h2(a3.y)));
                __half2 s2 = __hadd2(__hadd2(u2h2(a0.z), u2h2(a1.z)), __hadd2(u2h2(a2.z), u2h2(a3.z)));
                __half2 s3 = __hadd2(__hadd2(u2h2(a0.w), u2h2(a1.w)), __hadd2(u2h2(a2.w), u2h2(a3.w)));
                const float* bp = bias + chalf * 64 + c8;
                float4 b0 = *(const float4*)bp;
                float4 b1 = *(const float4*)(bp + 4);
                float2 f0 = __half22float2(s0), f1 = __half22float2(s1);
                float2 f2 = __half22float2(s2), f3 = __half22float2(s3);
                v.x = (int)pack2bf_f(0.25f * f0.x + b0.x, 0.25f * f0.y + b0.y);
                v.y = (int)pack2bf_f(0.25f * f1.x + b0.z, 0.25f * f1.y + b0.w);
                v.z = (int)pack2bf_f(0.25f * f2.x + b1.x, 0.25f * f2.y + b1.y);
                v.w = (int)pack2bf_f(0.25f * f3.x + b1.z, 0.25f * f3.y + b1.w);
            } else {
                v = (i32x4){0, 0, 0, 0};
            }
        }
        AsTile[row * 16 + (cb ^ (row & 7))] = v;
    }
    __syncthreads();

    f32x4 acc[2][4];
    #pragma unroll
    for (int i = 0; i < 2; ++i)
        #pragma unroll
        for (int j = 0; j < 4; ++j) acc[i][j] = (f32x4){0.f, 0.f, 0.f, 0.f};

    const s16x8* Bb = (const s16x8*)(Bt + (size_t)(h * 128 + wc * 64 + lr) * C);

    #pragma unroll
    for (int ks = 0; ks < 4; ++ks) {
        int cb = ks * 4 + ksel;
        s16x8 af[2], bf[4];
        #pragma unroll
        for (int i = 0; i < 2; ++i) {
            int rowl = wr * 32 + i * 16 + lr;
            af[i] = __builtin_bit_cast(s16x8, AsTile[rowl * 16 + (cb ^ (rowl & 7))]);
        }
        #pragma unroll
        for (int j = 0; j < 4; ++j) bf[j] = Bb[(size_t)(j * 16) * 16 + cb];
        #pragma unroll
        for (int i = 0; i < 2; ++i)
            #pragma unroll
            for (int j = 0; j < 4; ++j)
                acc[i][j] = __builtin_amdgcn_mfma_f32_16x16x32_bf16(bf[j], af[i], acc[i][j], 0, 0, 0);
    }

    float4 avj[4], dvj[4];
    #pragma unroll
    for (int j = 0; j < 4; ++j) {
        int cc = h * C + wc * 64 + j * 16 + ksel * 4;
        avj[j] = *(const float4*)&a_src[cc];
        dvj[j] = *(const float4*)&a_dst[cc];
    }

    unsigned short* slabp = Xh + (size_t)(h * 2 + wc) * Npad * 64;
    float ps[2] = {0.f, 0.f}, pd[2] = {0.f, 0.f};
    #pragma unroll
    for (int i = 0; i < 2; ++i) {
        int gr = r0 + wr * 32 + i * 16 + lr;
        #pragma unroll
        for (int j = 0; j < 4; ++j) {
            f32x4 a4 = acc[i][j];
            ps[i] += a4[0] * avj[j].x + a4[1] * avj[j].y + a4[2] * avj[j].z + a4[3] * avj[j].w;
            pd[i] += a4[0] * dvj[j].x + a4[1] * dvj[j].y + a4[2] * dvj[j].z + a4[3] * dvj[j].w;
            uint2 o;
            o.x = pkrtz_bits(a4[0], a4[1]);
            o.y = pkrtz_bits(a4[2], a4[3]);
            *(uint2*)(slabp + (size_t)gr * 64 + j * 16 + ksel * 4) = o;
        }
        ps[i] += __shfl_xor(ps[i], 16); ps[i] += __shfl_xor(ps[i], 32);
        pd[i] += __shfl_xor(pd[i], 16); pd[i] += __shfl_xor(pd[i], 32);
    }
    if (lane < 16) {
        #pragma unroll
        for (int i = 0; i < 2; ++i) {
            albuf[wr][i][lane][wc][0] = ps[i];
            albuf[wr][i][lane][wc][1] = pd[i];
        }
    }
    __syncthreads();

    if (t < 128) {
        int rid = t >> 1, which = t & 1;
        int wr2 = rid >> 5, rem = rid & 31, i2 = rem >> 4, l2 = rem & 15;
        float v = albuf[wr2][i2][l2][0][which] + albuf[wr2][i2][l2][1][which];
        int gr = r0 + wr2 * 32 + i2 * 16 + l2;
        if (gr < Nrows) {
            if (which) alpha_d[gr * H + h] = v;
            else       alpha_s[gr * H + h] = v;
        }
    }
}

// ---------------- gemm1 || scan (block 0 = scan, hidden under the GEMM grid) ----------------
__global__ __launch_bounds__(256) void gemm1_scan(const float* __restrict__ x, int N,
                                                  const unsigned short* __restrict__ Wt1,
                                                  const float* __restrict__ as1,
                                                  const float* __restrict__ ad1,
                                                  unsigned short* __restrict__ Xh,
                                                  float* __restrict__ alpha_s,
                                                  float* __restrict__ alpha_d, int Npad,
                                                  const int* __restrict__ counts,
                                                  int* __restrict__ row_off,
                                                  int* __restrict__ cursor) {
    __shared__ i32x4 AsTile[1024];
    __shared__ float albuf[2][2][16][2][2];
    int b = blockIdx.x;
    if (b == 0) {
        scan_body(counts, row_off, cursor, N, (int*)AsTile);
        return;
    }
    int gb = b - 1;
    gemm_body<true>(gb & 3, (gb >> 2) * 64, x, nullptr, N, Wt1, as1, ad1, Xh, alpha_s, alpha_d,
                    Npad, AsTile, albuf);
}

// ---------------- gemm2: fused combine1 (hout f16 -> head-mean + b1 -> A) ----------------
__global__ __launch_bounds__(256) void gemm2_kernel(const unsigned short* __restrict__ hout, int N,
                                                    const float* __restrict__ b1,
                                                    const unsigned short* __restrict__ Wt2,
                                                    const float* __restrict__ as2,
                                                    const float* __restrict__ ad2,
                                                    unsigned short* __restrict__ Xh,
                                                    float* __restrict__ alpha_s,
                                                    float* __restrict__ alpha_d, int Npad) {
    __shared__ i32x4 AsTile[1024];
    __shared__ float albuf[2][2][16][2][2];
    int gb = blockIdx.x;
    gemm_body<false>(gb & 3, (gb >> 2) * 64, hout, b1, N, Wt2, as2, ad2, Xh, alpha_s, alpha_d,
                     Npad, AsTile, albuf);
}

// ---------------- fused per-node max + per-edge packed weights: 4 nodes/wave, 16 lanes/node ----------------
// pk[h][e] = (f16(w) << 16) | src   (src < 65536)
__global__ __launch_bounds__(256) void attn_kernel(const float4* __restrict__ as4,
                                                   const float4* __restrict__ ad4,
                                                   const int* __restrict__ row_off,
                                                   const int* __restrict__ csr_src,
                                                   unsigned int* __restrict__ pk, int N, int M) {
    int n = blockIdx.x * 16 + (threadIdx.x >> 4);
    if (n >= N) return;
    int l = threadIdx.x & 15;
    int beg = row_off[n], end = row_off[n + 1];
    float4 mx = make_float4(-1e30f, -1e30f, -1e30f, -1e30f);
    for (int e = beg + l; e < end; e += 16) {
        float4 a = as4[csr_src[e]];
        mx.x = fmaxf(mx.x, a.x); mx.y = fmaxf(mx.y, a.y);
        mx.z = fmaxf(mx.z, a.z); mx.w = fmaxf(mx.w, a.w);
    }
    #pragma unroll
    for (int off = 8; off >= 1; off >>= 1) {
        mx.x = fmaxf(mx.x, __shfl_xor(mx.x, off));
        mx.y = fmaxf(mx.y, __shfl_xor(mx.y, off));
        mx.z = fmaxf(mx.z, __shfl_xor(mx.z, off));
        mx.w = fmaxf(mx.w, __shfl_xor(mx.w, off));
    }
    float4 d = ad4[n];
    float4 m;
    m.x = leaky(mx.x + d.x); m.y = leaky(mx.y + d.y);
    m.z = leaky(mx.z + d.z); m.w = leaky(mx.w + d.w);
    for (int e = beg + l; e < end; e += 16) {
        int s = csr_src[e];
        float4 a = as4[s];   // L1-hot from pass 0
        unsigned int su = (unsigned int)s;
        unsigned int w0 = (unsigned int)__half_as_ushort(__float2half(__expf(leaky(a.x + d.x) - m.x)));
        unsigned int w1 = (unsigned int)__half_as_ushort(__float2half(__expf(leaky(a.y + d.y) - m.y)));
        unsigned int w2 = (unsigned int)__half_as_ushort(__float2half(__expf(leaky(a.z + d.z) - m.z)));
        unsigned int w3 = (unsigned int)__half_as_ushort(__float2half(__expf(leaky(a.w + d.w) - m.w)));
        pk[e]                 = (w0 << 16) | su;
        pk[(size_t)M + e]     = (w1 << 16) | su;
        pk[(size_t)2 * M + e] = (w2 << 16) | su;
        pk[(size_t)3 * M + e] = (w3 << 16) | su;
    }
}

// ---------------- aggregation v14: full-head waves, head pinned to XCD pair {2h,2h+1} ----------------
// h = (blockIdx&7)>>1 -> under round-robin dispatch each head's 5.1 MB working set stays
// on 2 XCDs' L2s instead of being duplicated across all 8.
__global__ __launch_bounds__(256) void aggregate_v14(const unsigned short* __restrict__ xh,
                                                     const unsigned int* __restrict__ pk,
                                                     const int* __restrict__ row_off,
                                                     unsigned short* __restrict__ hout,
                                                     int N, int Npad, int M) {
    int i = blockIdx.x;
    int h = (i & 7) >> 1;
    int j = (i >> 3) * 2 + (i & 1);      // node-chunk index for this head
    int t = threadIdx.x;
    int wv = t >> 6;
    int lane = t & 63;
    int slot = lane >> 4;
    int l16 = lane & 15;
    int nbase = (j * 4 + wv) * 2;
    if (nbase >= N) return;

    i32x4 rx = make_rsrc(xh + (size_t)(h * 2) * Npad * 64, (unsigned int)Npad * 256u);
    i32x4 rp = make_rsrc(pk + (size_t)h * M, (unsigned int)M * 4u);
    int lcoff = (l16 >> 3) * (Npad * 128) + (l16 & 7) * 16;
    int slot4 = slot << 2;
    int nend = (nbase + 2 < N) ? nbase + 2 : N;

    for (int n = nbase; n < nend; ++n) {
        int beg = row_off[n], end = row_off[n + 1];
        __half2 a0 = u2h2(0), a1 = u2h2(0), a2 = u2h2(0), a3 = u2h2(0), den2 = u2h2(0);

        for (int ebase = beg; ebase < end; ebase += 64) {
            int p = amd_buf_load_i32(rp, (ebase + lane) << 2, 0, 0);
            int nrem = end - ebase;
            int jmax = ((nrem < 64 ? nrem : 64) + 7) >> 3;
            for (int jj = 0; jj < jmax; ++jj) {
                int addr = (jj << 5) + slot4;
                int sp0 = __builtin_amdgcn_ds_bpermute(addr, p);
                int sp1 = __builtin_amdgcn_ds_bpermute(addr + 16, p);
                int e0 = ebase + (jj << 3) + slot;
                i32x4 ga = amd_buf_load_i32x4(rx, ((sp0 & 0xffff) << 7) + lcoff, 0, 0);
                i32x4 gb = amd_buf_load_i32x4(rx, ((sp1 & 0xffff) << 7) + lcoff, 0, 0);
                unsigned int wa2 = __builtin_amdgcn_perm(sp0, sp0, 0x03020302);
                unsigned int wb2 = __builtin_amdgcn_perm(sp1, sp1, 0x03020302);
                if (e0 >= end) wa2 = 0u;
                if (e0 + 4 >= end) wb2 = 0u;
                __half2 wha = u2h2(wa2), whb = u2h2(wb2);
                a0 = __hfma2(wha, u2h2((unsigned int)ga.x), a0);
                a1 = __hfma2(wha, u2h2((unsigned int)ga.y), a1);
                a2 = __hfma2(wha, u2h2((unsigned int)ga.z), a2);
                a3 = __hfma2(wha, u2h2((unsigned int)ga.w), a3);
                a0 = __hfma2(whb, u2h2((unsigned int)gb.x), a0);
                a1 = __hfma2(whb, u2h2((unsigned int)gb.y), a1);
                a2 = __hfma2(whb, u2h2((unsigned int)gb.z), a2);
                a3 = __hfma2(whb, u2h2((unsigned int)gb.w), a3);
                den2 = __hadd2(den2, wha);
                den2 = __hadd2(den2, whb);
            }
        }

        // cross-slot reduce (lane bits 4,5): 5 packed values x 2 levels
        #pragma unroll
        for (int off = 16; off <= 32; off <<= 1) {
            a0 = __hadd2(a0, u2h2((unsigned int)__shfl_xor((int)h22u(a0), off)));
            a1 = __hadd2(a1, u2h2((unsigned int)__shfl_xor((int)h22u(a1), off)));
            a2 = __hadd2(a2, u2h2((unsigned int)__shfl_xor((int)h22u(a2), off)));
            a3 = __hadd2(a3, u2h2((unsigned int)__shfl_xor((int)h22u(a3), off)));
            den2 = __hadd2(den2, u2h2((unsigned int)__shfl_xor((int)h22u(den2), off)));
        }

        if (slot == 0) {
            float2 f0 = __half22float2(a0), f1 = __half22float2(a1);
            float2 f2 = __half22float2(a2), f3 = __half22float2(a3);
            float inv = 1.f / __half2float(__low2half(den2));
            uint4 o;
            o.x = pkrtz_bits(f0.x * inv, f0.y * inv);   // f16 out
            o.y = pkrtz_bits(f1.x * inv, f1.y * inv);
            o.z = pkrtz_bits(f2.x * inv, f2.y * inv);
            o.w = pkrtz_bits(f3.x * inv, f3.y * inv);
            ((uint4*)hout)[((size_t)(h * 2 + (l16 >> 3)) * Npad + n) * 8 + (l16 & 7)] = o;
        }
    }
}

// ---------------- head mean + bias -> bf16 feats (hout read as f16) + out init for pair ----------------
__global__ void combine_kernel(const unsigned short* __restrict__ hout,
                               const float* __restrict__ bias,
                               unsigned short* __restrict__ featsbf, int N, int Npad,
                               float* __restrict__ out, const float* __restrict__ fcb, int P) {
    int i = blockIdx.x * blockDim.x + threadIdx.x;   // dword index over [N][64]
    if (i < P) out[i] = fcb[0];
    if (i >= N * 64) return;
    int n = i >> 6, c2 = i & 63;
    int chalf = c2 >> 5, ld = c2 & 31;
    const unsigned int* hp = (const unsigned int*)hout;
    float lo = 0.f, hi = 0.f;
    #pragma unroll
    for (int h = 0; h < 4; ++h) {
        unsigned int v = hp[((size_t)(h * 2 + chalf) * Npad + n) * 32 + ld];
        float2 f = __half22float2(u2h2(v));
        lo += f.x; hi += f.y;
    }
    lo = 0.25f * lo + bias[c2 * 2];
    hi = 0.25f * hi + bias[c2 * 2 + 1];
    ((unsigned int*)featsbf)[(size_t)n * 64 + c2] = f2bf_bits(lo) | (f2bf_bits(hi) << 16);
}

// ---------------- pairwise scorer: chalf-split, XCD parity pinned, atomic combine ----------------
__global__ __launch_bounds__(256) void pair_kernel(const unsigned short* __restrict__ featsbf,
                                                   const float* __restrict__ x,
                                                   const int* __restrict__ idx, int P,
                                                   const float* __restrict__ fc_w,
                                                   float* __restrict__ out) {
    int chalf = blockIdx.x & 1;
    int p = (blockIdx.x >> 1) * 16 + (threadIdx.x >> 4);
    int l = threadIdx.x & 15;
    if (p >= P) return;
    int i0 = idx[p], i1 = idx[P + p];
    uint2 a = ((const uint2*)featsbf)[(size_t)i0 * 32 + chalf * 16 + l];
    uint2 b = ((const uint2*)featsbf)[(size_t)i1 * 32 + chalf * 16 + l];
    float s = bflo(a.x) * bflo(b.x) + bfhi(a.x) * bfhi(b.x)
            + bflo(a.y) * bflo(b.y) + bfhi(a.y) * bfhi(b.y);
    s += __shfl_xor(s, 1); s += __shfl_xor(s, 2);
    s += __shfl_xor(s, 4); s += __shfl_xor(s, 8);
    if (l == 0) {
        float v = fc_w[0] * s;
        if (chalf == 0) {
            float2 c0 = *(const float2*)&x[(size_t)i0 * 130];
            float2 c1 = *(const float2*)&x[(size_t)i1 * 130];
            float dx = c0.x - c1.x;
            float dy = c0.y - c1.y;
            v += fc_w[1] * (dx * dx + dy * dy);
        }
        atomicAdd(&out[p], v);
    }
}

extern "C" void kernel_launch(void* const* d_in, const int* in_sizes, int n_in,
                              void* d_out, int out_size, void* d_ws, size_t ws_size,
                              hipStream_t stream) {
    const float* x   = (const float*)d_in[0];
    const int*   ei  = (const int*)d_in[1];
    const int*   idx = (const int*)d_in[2];
    const float* W1  = (const float*)d_in[3];
    const float* as1 = (const float*)d_in[4];
    const float* ad1 = (const float*)d_in[5];
    const float* b1  = (const float*)d_in[6];
    const float* W2  = (const float*)d_in[7];
    const float* as2 = (const float*)d_in[8];
    const float* ad2 = (const float*)d_in[9];
    const float* b2  = (const float*)d_in[10];
    const float* fcw = (const float*)d_in[11];
    const float* fcb = (const float*)d_in[12];
    float* out = (float*)d_out;

    const int N = in_sizes[0] / 130;
    const int E = in_sizes[1] / 2;
    const int P = in_sizes[2] / 2;
    const int M = E + N;
    const int Npad = (N + 127) & ~127;

    char* ws = (char*)d_ws;
    size_t off = 0;
    auto alloc = [&](size_t bytes) -> void* {
        void* p = ws + off;
        off += (bytes + 255) & ~(size_t)255;
        return p;
    };
    unsigned short* xh_f16  = (unsigned short*)alloc((size_t)Npad * FOUT * 2);
    unsigned short* hout    = (unsigned short*)alloc((size_t)Npad * FOUT * 2);
    unsigned short* featsbf = (unsigned short*)alloc((size_t)Npad * C * 2);
    unsigned short* Wt1     = (unsigned short*)alloc((size_t)128 * FOUT * 2);
    unsigned short* Wt2     = (unsigned short*)alloc((size_t)128 * FOUT * 2);
    float*          alpha_s = (float*)alloc((size_t)N * H * 4);
    float*          alpha_d = (float*)alloc((size_t)N * H * 4);
    unsigned int*   pk      = (unsigned int*)alloc((size_t)M * H * 4);
    int*            row_off = (int*)alloc((size_t)(N + 1) * 4);
    int*            cursor  = (int*)alloc((size_t)N * 4);
    int*            counts  = (int*)alloc((size_t)N * 4);
    int*            csr_src = (int*)alloc((size_t)M * 4);

    const int zeroBlocks = (N + 255) / 256;
    const int histBlocks = (M + 255) / 256;
    const int gemmBlocks = 4 * (Npad / 64);
    const int nchunks = (N + 7) / 8;
    int aggGrid = ((nchunks + 1) / 2) * 8;
    int cmbGrid = (N * 64 + 255) / 256;

    // (weights-convert || zero counts), hist, (gemm1 || scan), scatter
    prep_zero<<<256 + zeroBlocks, 256, 0, stream>>>(W1, W2, Wt1, Wt2, counts, N);
    hist_kernel<<<histBlocks, 256, 0, stream>>>(ei, E, N, counts);
    gemm1_scan<<<1 + gemmBlocks, 256, 0, stream>>>(x, N, Wt1, as1, ad1, xh_f16,
                                                   alpha_s, alpha_d, Npad,
                                                   counts, row_off, cursor);
    scatter_kernel<<<histBlocks, 256, 0, stream>>>(ei, E, N, cursor, csr_src);

    // layer 1
    attn_kernel<<<(N + 15) / 16, 256, 0, stream>>>((const float4*)alpha_s, (const float4*)alpha_d,
                                                   row_off, csr_src, pk, N, M);
    aggregate_v14<<<aggGrid, 256, 0, stream>>>(xh_f16, pk, row_off, hout, N, Npad, M);

    // layer 2 (gemm2 reads hout f16 directly, fused combine1 with bias b1)
    gemm2_kernel<<<gemmBlocks, 256, 0, stream>>>(hout, N, b1, Wt2, as2, ad2, xh_f16,
                                                 alpha_s, alpha_d, Npad);
    attn_kernel<<<(N + 15) / 16, 256, 0, stream>>>((const float4*)alpha_s, (const float4*)alpha_d,
                                                   row_off, csr_src, pk, N, M);
    aggregate_v14<<<aggGrid, 256, 0, stream>>>(xh_f16, pk, row_off, hout, N, Npad, M);
    combine_kernel<<<cmbGrid, 256, 0, stream>>>(hout, b2, featsbf, N, Npad, out, fcb, P);

    // pairwise output (chalf-split, accumulates into out initialized by combine above)
    pair_kernel<<<((P + 15) / 16) * 2, 256, 0, stream>>>(featsbf, x, idx, P, fcw, out);
}